// Round 1
// baseline (255.744 us; speedup 1.0000x reference)
//
#include <hip/hip_runtime.h>

#define BS 16
#define NN 50000
#define SEQ 9
#define IC 32
#define OC 32
#define FAN (IC * (SEQ + 1))   // 320
#define NPB 128                // nodes per main-kernel block
#define GROUPS 64              // max-prepass groups per batch

__device__ __forceinline__ float4 fmax4(float4 a, float4 b) {
  return make_float4(fmaxf(a.x, b.x), fmaxf(a.y, b.y), fmaxf(a.z, b.z), fmaxf(a.w, b.w));
}

// Pass 1: per-(batch, group) column max over node stripes. Coalesced float4 reads.
__global__ __launch_bounds__(256) void kmax_partial(const float* __restrict__ x,
                                                    float* __restrict__ partial) {
  int bg = blockIdx.x;
  int b = bg >> 6, g = bg & 63;
  int t = threadIdx.x;
  int q = t & 7;   // float4 index within a 32-float row
  int r = t >> 3;  // 32 rows per iteration
  const float4* xb = (const float4*)(x + (size_t)b * NN * IC);
  float4 m = make_float4(-INFINITY, -INFINITY, -INFINITY, -INFINITY);
  for (int n = g * 32 + r; n < NN; n += GROUPS * 32) {
    m = fmax4(m, xb[n * 8 + q]);
  }
  __shared__ float4 sm[32][8];
  sm[r][q] = m;
  __syncthreads();
  for (int s = 16; s >= 1; s >>= 1) {
    if (r < s) sm[r][q] = fmax4(sm[r][q], sm[r + s][q]);
    __syncthreads();
  }
  if (t < 8) ((float4*)(partial + bg * IC))[t] = sm[0][t];
}

// Pass 2: finish max, fold bias + gmax @ W[:,288:320] into gcontrib[b][o].
__global__ __launch_bounds__(64) void kmax_final(const float* __restrict__ partial,
                                                 const float* __restrict__ W,
                                                 const float* __restrict__ bias,
                                                 float* __restrict__ gcontrib) {
  int b = blockIdx.x, t = threadIdx.x;
  __shared__ float gmax[IC];
  if (t < IC) {
    float m = -INFINITY;
    for (int g = 0; g < GROUPS; g++) m = fmaxf(m, partial[(b * GROUPS + g) * IC + t]);
    gmax[t] = m;
  }
  __syncthreads();
  if (t < OC) {
    float acc = bias[t];
#pragma unroll
    for (int c = 0; c < IC; c++) acc += gmax[c] * W[t * FAN + SEQ * IC + c];
    gcontrib[b * OC + t] = acc;
  }
}

// Main: gather-GEMM. Block = 1 batch x 128 nodes; thread = 4 nodes x 4 outs.
__global__ __launch_bounds__(256) void kmain(const float* __restrict__ x,
                                             const int* __restrict__ idx,
                                             const float* __restrict__ W,
                                             const float* __restrict__ gcontrib,
                                             float* __restrict__ out) {
  __shared__ __align__(16) float At[IC][NPB];   // 16 KB, [f][node] (transposed!)
  __shared__ __align__(16) float Wt[IC][OC];    //  4 KB, [f][o] (transposed)
  __shared__ int sidx[NPB * SEQ];               // 4.5 KB
  int b = blockIdx.y;
  int nb = blockIdx.x * NPB;
  int nvalid = min(NPB, NN - nb);
  int t = threadIdx.x;
  const float* xb = x + (size_t)b * NN * IC;

  for (int k = t; k < nvalid * SEQ; k += 256) sidx[k] = idx[nb * SEQ + k];

  int oy = t & 7, nx = t >> 3;  // compute mapping: oy fast -> coalesced stores
  int nr = t >> 1, h = t & 1;   // gather mapping: 2 threads x 64B per node row
  int ow = t >> 3, cq = t & 7;  // W staging mapping
  float4 acc[4];
  acc[0] = acc[1] = acc[2] = acc[3] = make_float4(0.f, 0.f, 0.f, 0.f);

  __syncthreads();  // sidx ready

  for (int s = 0; s < SEQ; s++) {
    // stage Wt[f][o] = W[o][s*32 + f]
    {
      float4 w4 = *(const float4*)&W[ow * FAN + s * IC + cq * 4];
      Wt[cq * 4 + 0][ow] = w4.x;
      Wt[cq * 4 + 1][ow] = w4.y;
      Wt[cq * 4 + 2][ow] = w4.z;
      Wt[cq * 4 + 3][ow] = w4.w;
    }
    // gather At[f][n] = x[b][ sidx[n*9+s] ][f]
    {
      int j = (nr < nvalid) ? sidx[nr * SEQ + s] : 0;
      const float4* row = (const float4*)(xb + (size_t)j * IC);
#pragma unroll
      for (int k = 0; k < 4; k++) {
        float4 v = row[h * 4 + k];
        int f0 = h * 16 + k * 4;
        At[f0 + 0][nr] = v.x;
        At[f0 + 1][nr] = v.y;
        At[f0 + 2][nr] = v.z;
        At[f0 + 3][nr] = v.w;
      }
    }
    __syncthreads();
#pragma unroll 8
    for (int f = 0; f < IC; f++) {
      float4 a = *(const float4*)&At[f][nx * 4];
      float4 w = *(const float4*)&Wt[f][oy * 4];
      acc[0].x += a.x * w.x; acc[0].y += a.x * w.y; acc[0].z += a.x * w.z; acc[0].w += a.x * w.w;
      acc[1].x += a.y * w.x; acc[1].y += a.y * w.y; acc[1].z += a.y * w.z; acc[1].w += a.y * w.w;
      acc[2].x += a.z * w.x; acc[2].y += a.z * w.y; acc[2].z += a.z * w.z; acc[2].w += a.z * w.w;
      acc[3].x += a.w * w.x; acc[3].y += a.w * w.y; acc[3].z += a.w * w.z; acc[3].w += a.w * w.w;
    }
    __syncthreads();
  }

  float4 gc = *(const float4*)&gcontrib[b * OC + oy * 4];
#pragma unroll
  for (int i = 0; i < 4; i++) {
    int n = nx * 4 + i;
    if (n < nvalid) {
      float4 r = make_float4(acc[i].x + gc.x, acc[i].y + gc.y, acc[i].z + gc.z, acc[i].w + gc.w);
      *(float4*)&out[((size_t)b * NN + nb + n) * OC + oy * 4] = r;
    }
  }
}

extern "C" void kernel_launch(void* const* d_in, const int* in_sizes, int n_in,
                              void* d_out, int out_size, void* d_ws, size_t ws_size,
                              hipStream_t stream) {
  const float* x = (const float*)d_in[0];
  const int* idx = (const int*)d_in[1];
  const float* W = (const float*)d_in[2];
  const float* bias = (const float*)d_in[3];
  float* out = (float*)d_out;

  float* partial = (float*)d_ws;                 // 16*64*32 = 32768 floats
  float* gcontrib = partial + BS * GROUPS * IC;  // 16*32 = 512 floats

  kmax_partial<<<BS * GROUPS, 256, 0, stream>>>(x, partial);
  kmax_final<<<BS, 64, 0, stream>>>(partial, W, bias, gcontrib);

  dim3 grid((NN + NPB - 1) / NPB, BS);  // (391, 16)
  kmain<<<grid, 256, 0, stream>>>(x, idx, W, gcontrib, out);
}

// Round 2
// 160.188 us; speedup vs baseline: 1.5965x; 1.5965x over previous
//
#include <hip/hip_runtime.h>

#define BS 16
#define NN 50000
#define SEQ 9
#define IC 32
#define OC 32
#define FAN 320
#define GROUPS 64
#define MTILES_PER_B (NN / 16)          // 3125
#define TOTAL_TILES (BS * MTILES_PER_B) // 50000
#define KBLK 1024                       // kmfma blocks (4 waves each)

typedef __attribute__((ext_vector_type(8))) short short8;
typedef __attribute__((ext_vector_type(4))) float f32x4;

__device__ __forceinline__ float4 fmax4(float4 a, float4 b) {
  return make_float4(fmaxf(a.x, b.x), fmaxf(a.y, b.y), fmaxf(a.z, b.z), fmaxf(a.w, b.w));
}

// pack2: [15:0]=bf16(a), [31:16]=bf16(b). (If HW order is swapped, A and B use the
// same k-permutation -> dot product invariant.)
__device__ __forceinline__ unsigned pk_bf16(float a, float b) {
  unsigned r;
  asm("v_cvt_pk_bf16_f32 %0, %1, %2" : "=v"(r) : "v"(a), "v"(b));
  return r;
}

// split 8 floats into hi/lo bf16 pairs (packed 2-per-uint, element order preserved)
__device__ __forceinline__ void split8(const float* v, unsigned* hi, unsigned* lo) {
#pragma unroll
  for (int i = 0; i < 4; i++) {
    float a = v[2 * i], b = v[2 * i + 1];
    unsigned h = pk_bf16(a, b);
    float fa = __builtin_bit_cast(float, h << 16);
    float fb = __builtin_bit_cast(float, h & 0xFFFF0000u);
    lo[i] = pk_bf16(a - fa, b - fb);
    hi[i] = h;
  }
}

union FragU { unsigned u[4]; short8 v; };

// ---------- Pass 1: per-(batch, group) column max ----------
__global__ __launch_bounds__(256) void kmax_partial(const float* __restrict__ x,
                                                    float* __restrict__ partial) {
  int bg = blockIdx.x;
  int b = bg >> 6, g = bg & 63;
  int t = threadIdx.x;
  int q = t & 7, r = t >> 3;
  const float4* xb = (const float4*)(x + (size_t)b * NN * IC);
  float4 m = make_float4(-INFINITY, -INFINITY, -INFINITY, -INFINITY);
  for (int n = g * 32 + r; n < NN; n += GROUPS * 32) m = fmax4(m, xb[n * 8 + q]);
  __shared__ float4 sm[32][8];
  sm[r][q] = m;
  __syncthreads();
  for (int s = 16; s >= 1; s >>= 1) {
    if (r < s) sm[r][q] = fmax4(sm[r][q], sm[r + s][q]);
    __syncthreads();
  }
  if (t < 8) ((float4*)(partial + bg * IC))[t] = sm[0][t];
}

// ---------- Pass 2: finish max, fold bias + gmax @ W[:,288:320] ----------
__global__ __launch_bounds__(64) void kmax_final(const float* __restrict__ partial,
                                                 const float* __restrict__ W,
                                                 const float* __restrict__ bias,
                                                 float* __restrict__ gcontrib) {
  int b = blockIdx.x, t = threadIdx.x;
  __shared__ float gmax[IC];
  if (t < IC) {
    float m = -INFINITY;
    for (int g = 0; g < GROUPS; g++) m = fmaxf(m, partial[(b * GROUPS + g) * IC + t]);
    gmax[t] = m;
  }
  __syncthreads();
  if (t < OC) {
    float acc = bias[t];
#pragma unroll
    for (int c = 0; c < IC; c++) acc += gmax[c] * W[t * FAN + SEQ * IC + c];
    gcontrib[b * OC + t] = acc;
  }
}

// ---------- Pass 3: split W[:,0:288] into hi/lo bf16, MFMA-fragment order ----------
// wfrag layout (uints): [part(hi=0,lo=1)][s][ntile][lane][4]
// element (s,n,l,e):  o = n*16 + (l&15), k = s*32 + (l>>4)*8 + e
__global__ __launch_bounds__(256) void kconvW(const float* __restrict__ W,
                                              unsigned* __restrict__ wfrag) {
  int t = threadIdx.x;
  for (int slot = t; slot < SEQ * 2 * 64; slot += 256) {
    int s = slot >> 7, rem = slot & 127;
    int n = rem >> 6, l = rem & 63;
    int o = n * 16 + (l & 15);
    int k0 = s * 32 + (l >> 4) * 8;
    const float* p = W + o * FAN + k0;
    float v[8];
#pragma unroll
    for (int e = 0; e < 8; e++) v[e] = p[e];
    unsigned hi[4], lo[4];
    split8(v, hi, lo);
#pragma unroll
    for (int i = 0; i < 4; i++) {
      wfrag[slot * 4 + i] = hi[i];
      wfrag[(SEQ * 2 * 64 + slot) * 4 + i] = lo[i];
    }
  }
}

// ---------- Main: gather + split-bf16 MFMA GEMM ----------
// Wave computes a 16-node x 32-out tile. A gathered direct global->reg.
__global__ __launch_bounds__(256) void kmfma(const float* __restrict__ x,
                                             const int* __restrict__ idx,
                                             const float* __restrict__ gcontrib,
                                             const unsigned* __restrict__ wfrag,
                                             float* __restrict__ out) {
  __shared__ __align__(16) unsigned wl[2 * SEQ * 2 * 64 * 4]; // 36864 B
  int t = threadIdx.x;
  for (int i = t; i < 2 * SEQ * 2 * 64 * 4; i += 256) wl[i] = wfrag[i];
  __syncthreads();

  int wid = t >> 6, l = t & 63;
  int lane_lo = l & 15, kg = l >> 4;

  for (int tile = blockIdx.x * 4 + wid; tile < TOTAL_TILES; tile += KBLK * 4) {
    int b = tile / MTILES_PER_B;
    int nb = (tile % MTILES_PER_B) * 16;
    const float* xb = x + (size_t)b * NN * IC;

    int j[SEQ];
    const int* ip = idx + (nb + lane_lo) * SEQ;
#pragma unroll
    for (int s = 0; s < SEQ; s++) j[s] = ip[s];

    f32x4 acc0 = {0.f, 0.f, 0.f, 0.f};
    f32x4 acc1 = {0.f, 0.f, 0.f, 0.f};

#pragma unroll
    for (int s = 0; s < SEQ; s++) {
      const float4* row = (const float4*)(xb + (size_t)j[s] * IC + kg * 8);
      float4 v0 = row[0], v1 = row[1];
      float v[8] = {v0.x, v0.y, v0.z, v0.w, v1.x, v1.y, v1.z, v1.w};
      FragU ah, al;
      split8(v, ah.u, al.u);

      short8 bh0 = *(const short8*)&wl[(s * 2 + 0) * 256 + (l << 2)];
      short8 bh1 = *(const short8*)&wl[(s * 2 + 1) * 256 + (l << 2)];
      short8 bl0 = *(const short8*)&wl[(SEQ * 2 + s * 2 + 0) * 256 + (l << 2)];
      short8 bl1 = *(const short8*)&wl[(SEQ * 2 + s * 2 + 1) * 256 + (l << 2)];

      acc0 = __builtin_amdgcn_mfma_f32_16x16x32_bf16(ah.v, bh0, acc0, 0, 0, 0);
      acc0 = __builtin_amdgcn_mfma_f32_16x16x32_bf16(ah.v, bl0, acc0, 0, 0, 0);
      acc0 = __builtin_amdgcn_mfma_f32_16x16x32_bf16(al.v, bh0, acc0, 0, 0, 0);
      acc1 = __builtin_amdgcn_mfma_f32_16x16x32_bf16(ah.v, bh1, acc1, 0, 0, 0);
      acc1 = __builtin_amdgcn_mfma_f32_16x16x32_bf16(ah.v, bl1, acc1, 0, 0, 0);
      acc1 = __builtin_amdgcn_mfma_f32_16x16x32_bf16(al.v, bh1, acc1, 0, 0, 0);
    }

    // D layout: col = lane&15, row = (lane>>4)*4 + reg  [m89-verified]
    float g0 = gcontrib[b * OC + lane_lo];
    float g1 = gcontrib[b * OC + 16 + lane_lo];
#pragma unroll
    for (int jj = 0; jj < 4; jj++) {
      size_t o = ((size_t)b * NN + nb + kg * 4 + jj) * OC;
      out[o + lane_lo] = acc0[jj] + g0;
      out[o + 16 + lane_lo] = acc1[jj] + g1;
    }
  }
}

extern "C" void kernel_launch(void* const* d_in, const int* in_sizes, int n_in,
                              void* d_out, int out_size, void* d_ws, size_t ws_size,
                              hipStream_t stream) {
  const float* x = (const float*)d_in[0];
  const int* idx = (const int*)d_in[1];
  const float* W = (const float*)d_in[2];
  const float* bias = (const float*)d_in[3];
  float* out = (float*)d_out;

  float* partial = (float*)d_ws;                   // 32768 floats
  float* gcontrib = partial + BS * GROUPS * IC;    // 512 floats
  unsigned* wfrag = (unsigned*)(gcontrib + BS * OC); // 9216 uints (36864 B)

  kmax_partial<<<BS * GROUPS, 256, 0, stream>>>(x, partial);
  kmax_final<<<BS, 64, 0, stream>>>(partial, W, bias, gcontrib);
  kconvW<<<1, 256, 0, stream>>>(W, wfrag);
  kmfma<<<KBLK, 256, 0, stream>>>(x, idx, gcontrib, wfrag, out);
}

// Round 3
// 153.183 us; speedup vs baseline: 1.6695x; 1.0457x over previous
//
#include <hip/hip_runtime.h>

#define BS 16
#define NN 50000
#define SEQ 9
#define IC 32
#define OC 32
#define FAN 320
#define GROUPS 64
#define MTILES_PER_B (NN / 16)          // 3125
#define TPX (2 * MTILES_PER_B)          // tiles per XCD (2 batches) = 6250
#define KBLK 1024                       // kmfma blocks (4 waves each)
#define WPX (KBLK / 8 * 4)              // waves per XCD = 512

typedef __attribute__((ext_vector_type(8))) short short8;
typedef __attribute__((ext_vector_type(4))) float f32x4;

__device__ __forceinline__ float4 fmax4(float4 a, float4 b) {
  return make_float4(fmaxf(a.x, b.x), fmaxf(a.y, b.y), fmaxf(a.z, b.z), fmaxf(a.w, b.w));
}

// pack2: [15:0]=bf16(a), [31:16]=bf16(b). A and B use the same k-permutation.
__device__ __forceinline__ unsigned pk_bf16(float a, float b) {
  unsigned r;
  asm("v_cvt_pk_bf16_f32 %0, %1, %2" : "=v"(r) : "v"(a), "v"(b));
  return r;
}

// split 8 floats into hi/lo bf16 pairs (packed 2-per-uint, element order preserved)
__device__ __forceinline__ void split8(const float* v, unsigned* hi, unsigned* lo) {
#pragma unroll
  for (int i = 0; i < 4; i++) {
    float a = v[2 * i], b = v[2 * i + 1];
    unsigned h = pk_bf16(a, b);
    float fa = __builtin_bit_cast(float, h << 16);
    float fb = __builtin_bit_cast(float, h & 0xFFFF0000u);
    lo[i] = pk_bf16(a - fa, b - fb);
    hi[i] = h;
  }
}

union FragU { unsigned u[4]; short8 v; };

// ---------- Pass 1: per-(batch, group) column max ----------
__global__ __launch_bounds__(256) void kmax_partial(const float* __restrict__ x,
                                                    float* __restrict__ partial) {
  int bg = blockIdx.x;
  int b = bg >> 6, g = bg & 63;
  int t = threadIdx.x;
  int q = t & 7, r = t >> 3;
  const float4* xb = (const float4*)(x + (size_t)b * NN * IC);
  float4 m = make_float4(-INFINITY, -INFINITY, -INFINITY, -INFINITY);
  for (int n = g * 32 + r; n < NN; n += GROUPS * 32) m = fmax4(m, xb[n * 8 + q]);
  __shared__ float4 sm[32][8];
  sm[r][q] = m;
  __syncthreads();
  for (int s = 16; s >= 1; s >>= 1) {
    if (r < s) sm[r][q] = fmax4(sm[r][q], sm[r + s][q]);
    __syncthreads();
  }
  if (t < 8) ((float4*)(partial + bg * IC))[t] = sm[0][t];
}

// ---------- Pass 2: finish max, fold bias + gmax @ W[:,288:320] ----------
__global__ __launch_bounds__(64) void kmax_final(const float* __restrict__ partial,
                                                 const float* __restrict__ W,
                                                 const float* __restrict__ bias,
                                                 float* __restrict__ gcontrib) {
  int b = blockIdx.x, t = threadIdx.x;
  __shared__ float gmax[IC];
  if (t < IC) {
    float m = -INFINITY;
    for (int g = 0; g < GROUPS; g++) m = fmaxf(m, partial[(b * GROUPS + g) * IC + t]);
    gmax[t] = m;
  }
  __syncthreads();
  if (t < OC) {
    float acc = bias[t];
#pragma unroll
    for (int c = 0; c < IC; c++) acc += gmax[c] * W[t * FAN + SEQ * IC + c];
    gcontrib[b * OC + t] = acc;
  }
}

// ---------- Pass 3: split W[:,0:288] into hi/lo bf16, MFMA-fragment order ----------
// wfrag layout (uints): [part(hi=0,lo=1)][s][ntile][lane][4]
// element (s,n,l,e):  o = n*16 + (l&15), k = s*32 + (l>>4)*8 + e
__global__ __launch_bounds__(256) void kconvW(const float* __restrict__ W,
                                              unsigned* __restrict__ wfrag) {
  int t = threadIdx.x;
  for (int slot = t; slot < SEQ * 2 * 64; slot += 256) {
    int s = slot >> 7, rem = slot & 127;
    int n = rem >> 6, l = rem & 63;
    int o = n * 16 + (l & 15);
    int k0 = s * 32 + (l >> 4) * 8;
    const float* p = W + o * FAN + k0;
    float v[8];
#pragma unroll
    for (int e = 0; e < 8; e++) v[e] = p[e];
    unsigned hi[4], lo[4];
    split8(v, hi, lo);
#pragma unroll
    for (int i = 0; i < 4; i++) {
      wfrag[slot * 4 + i] = hi[i];
      wfrag[(SEQ * 2 * 64 + slot) * 4 + i] = lo[i];
    }
  }
}

// ---------- Main: gather + split-bf16 MFMA GEMM, XCD-batch-coherent ----------
__global__ __launch_bounds__(256) void kmfma(const float* __restrict__ x,
                                             const int* __restrict__ idx,
                                             const float* __restrict__ gcontrib,
                                             const unsigned* __restrict__ wfrag,
                                             float* __restrict__ out) {
  __shared__ __align__(16) unsigned wl[2 * SEQ * 2 * 64 * 4]; // 36864 B
  int t = threadIdx.x;
  for (int i = t; i < 2 * SEQ * 2 * 64 * 4; i += 256) wl[i] = wfrag[i];
  __syncthreads();

  int bid = blockIdx.x;
  int xcd = bid & 7, slot = bid >> 3;         // bid%8 -> XCD (round-robin dispatch)
  int wid = t >> 6, l = t & 63;
  int ws = slot * 4 + wid;                    // wave slot within XCD, 0..511
  int lane_lo = l & 15, kg = l >> 4;

  for (int tt = ws; tt < TPX; tt += WPX) {
    int loc = tt, bloc = 0;
    if (loc >= MTILES_PER_B) { loc -= MTILES_PER_B; bloc = 1; }
    int b = 2 * xcd + bloc;
    int nb = loc * 16;
    const float* xb = x + (size_t)b * NN * IC;

    int j[SEQ];
    const int* ip = idx + (nb + lane_lo) * SEQ;
#pragma unroll
    for (int s = 0; s < SEQ; s++) j[s] = ip[s];

    // hoist ALL gather loads (18 x float4) so they overlap
    float4 r0[SEQ], r1[SEQ];
#pragma unroll
    for (int s = 0; s < SEQ; s++) {
      const float4* row = (const float4*)(xb + (size_t)j[s] * IC + kg * 8);
      r0[s] = row[0];
      r1[s] = row[1];
    }

    f32x4 acc0 = {0.f, 0.f, 0.f, 0.f};
    f32x4 acc1 = {0.f, 0.f, 0.f, 0.f};

#pragma unroll
    for (int s = 0; s < SEQ; s++) {
      float v[8] = {r0[s].x, r0[s].y, r0[s].z, r0[s].w,
                    r1[s].x, r1[s].y, r1[s].z, r1[s].w};
      FragU ah, al;
      split8(v, ah.u, al.u);

      short8 bh0 = *(const short8*)&wl[(s * 2 + 0) * 256 + (l << 2)];
      short8 bh1 = *(const short8*)&wl[(s * 2 + 1) * 256 + (l << 2)];
      short8 bl0 = *(const short8*)&wl[(SEQ * 2 + s * 2 + 0) * 256 + (l << 2)];
      short8 bl1 = *(const short8*)&wl[(SEQ * 2 + s * 2 + 1) * 256 + (l << 2)];

      acc0 = __builtin_amdgcn_mfma_f32_16x16x32_bf16(ah.v, bh0, acc0, 0, 0, 0);
      acc0 = __builtin_amdgcn_mfma_f32_16x16x32_bf16(ah.v, bl0, acc0, 0, 0, 0);
      acc0 = __builtin_amdgcn_mfma_f32_16x16x32_bf16(al.v, bh0, acc0, 0, 0, 0);
      acc1 = __builtin_amdgcn_mfma_f32_16x16x32_bf16(ah.v, bh1, acc1, 0, 0, 0);
      acc1 = __builtin_amdgcn_mfma_f32_16x16x32_bf16(ah.v, bl1, acc1, 0, 0, 0);
      acc1 = __builtin_amdgcn_mfma_f32_16x16x32_bf16(al.v, bh1, acc1, 0, 0, 0);
    }

    // D layout: col = lane&15, row = (lane>>4)*4 + reg  [m89-verified]
    float g0 = gcontrib[b * OC + lane_lo];
    float g1 = gcontrib[b * OC + 16 + lane_lo];
#pragma unroll
    for (int jj = 0; jj < 4; jj++) {
      size_t o = ((size_t)b * NN + nb + kg * 4 + jj) * OC;
      __builtin_nontemporal_store(acc0[jj] + g0, &out[o + lane_lo]);
      __builtin_nontemporal_store(acc1[jj] + g1, &out[o + 16 + lane_lo]);
    }
  }
}

extern "C" void kernel_launch(void* const* d_in, const int* in_sizes, int n_in,
                              void* d_out, int out_size, void* d_ws, size_t ws_size,
                              hipStream_t stream) {
  const float* x = (const float*)d_in[0];
  const int* idx = (const int*)d_in[1];
  const float* W = (const float*)d_in[2];
  const float* bias = (const float*)d_in[3];
  float* out = (float*)d_out;

  float* partial = (float*)d_ws;                     // 32768 floats
  float* gcontrib = partial + BS * GROUPS * IC;      // 512 floats
  unsigned* wfrag = (unsigned*)(gcontrib + BS * OC); // 9216 uints (36864 B)

  kmax_partial<<<BS * GROUPS, 256, 0, stream>>>(x, partial);
  kmax_final<<<BS, 64, 0, stream>>>(partial, W, bias, gcontrib);
  kconvW<<<1, 256, 0, stream>>>(W, wfrag);
  kmfma<<<KBLK, 256, 0, stream>>>(x, idx, gcontrib, wfrag, out);
}

// Round 4
// 150.770 us; speedup vs baseline: 1.6962x; 1.0160x over previous
//
#include <hip/hip_runtime.h>

#define BS 16
#define NN 50000
#define SEQ 9
#define IC 32
#define OC 32
#define FAN 320
#define GROUPS 64
#define MTILES_PER_B (NN / 16)          // 3125
#define TPX (2 * MTILES_PER_B)          // tiles per XCD (2 batches) = 6250
#define KBLK 2048                       // kmfma blocks (4 waves each) -> 8 blocks/CU
#define WPX (KBLK / 8 * 4)              // waves per XCD = 1024
#define WLN (SEQ * 2 * 64 * 4)          // wl uints (hi only) = 4608 -> 18432 B

typedef __attribute__((ext_vector_type(8))) short short8;
typedef __attribute__((ext_vector_type(4))) float f32x4;

__device__ __forceinline__ float4 fmax4(float4 a, float4 b) {
  return make_float4(fmaxf(a.x, b.x), fmaxf(a.y, b.y), fmaxf(a.z, b.z), fmaxf(a.w, b.w));
}

// pack2: [15:0]=bf16(a), [31:16]=bf16(b). A and B use the same k-permutation.
__device__ __forceinline__ unsigned pk_bf16(float a, float b) {
  unsigned r;
  asm("v_cvt_pk_bf16_f32 %0, %1, %2" : "=v"(r) : "v"(a), "v"(b));
  return r;
}

// split 8 floats into hi/lo bf16 pairs (packed 2-per-uint, element order preserved)
__device__ __forceinline__ void split8(const float* v, unsigned* hi, unsigned* lo) {
#pragma unroll
  for (int i = 0; i < 4; i++) {
    float a = v[2 * i], b = v[2 * i + 1];
    unsigned h = pk_bf16(a, b);
    float fa = __builtin_bit_cast(float, h << 16);
    float fb = __builtin_bit_cast(float, h & 0xFFFF0000u);
    lo[i] = pk_bf16(a - fa, b - fb);
    hi[i] = h;
  }
}

// hi-only pack of 8 floats
__device__ __forceinline__ void pack8(const float* v, unsigned* hi) {
#pragma unroll
  for (int i = 0; i < 4; i++) hi[i] = pk_bf16(v[2 * i], v[2 * i + 1]);
}

union FragU { unsigned u[4]; short8 v; };

// ---------- Pass 1: per-(batch, group) column max ----------
__global__ __launch_bounds__(256) void kmax_partial(const float* __restrict__ x,
                                                    float* __restrict__ partial) {
  int bg = blockIdx.x;
  int b = bg >> 6, g = bg & 63;
  int t = threadIdx.x;
  int q = t & 7, r = t >> 3;
  const float4* xb = (const float4*)(x + (size_t)b * NN * IC);
  float4 m = make_float4(-INFINITY, -INFINITY, -INFINITY, -INFINITY);
  for (int n = g * 32 + r; n < NN; n += GROUPS * 32) m = fmax4(m, xb[n * 8 + q]);
  __shared__ float4 sm[32][8];
  sm[r][q] = m;
  __syncthreads();
  for (int s = 16; s >= 1; s >>= 1) {
    if (r < s) sm[r][q] = fmax4(sm[r][q], sm[r + s][q]);
    __syncthreads();
  }
  if (t < 8) ((float4*)(partial + bg * IC))[t] = sm[0][t];
}

// ---------- Pass 2: finish max, fold bias + gmax @ W[:,288:320] ----------
__global__ __launch_bounds__(64) void kmax_final(const float* __restrict__ partial,
                                                 const float* __restrict__ W,
                                                 const float* __restrict__ bias,
                                                 float* __restrict__ gcontrib) {
  int b = blockIdx.x, t = threadIdx.x;
  __shared__ float gmax[IC];
  if (t < IC) {
    float m = -INFINITY;
    for (int g = 0; g < GROUPS; g++) m = fmaxf(m, partial[(b * GROUPS + g) * IC + t]);
    gmax[t] = m;
  }
  __syncthreads();
  if (t < OC) {
    float acc = bias[t];
#pragma unroll
    for (int c = 0; c < IC; c++) acc += gmax[c] * W[t * FAN + SEQ * IC + c];
    gcontrib[b * OC + t] = acc;
  }
}

// ---------- Pass 3: W[:,0:288] -> bf16 (hi only), MFMA-fragment order ----------
// wfrag layout (uints): [s][ntile][lane][4]
// element (s,n,l,e):  o = n*16 + (l&15), k = s*32 + (l>>4)*8 + e
__global__ __launch_bounds__(256) void kconvW(const float* __restrict__ W,
                                              unsigned* __restrict__ wfrag) {
  int t = threadIdx.x;
  for (int slot = t; slot < SEQ * 2 * 64; slot += 256) {
    int s = slot >> 7, rem = slot & 127;
    int n = rem >> 6, l = rem & 63;
    int o = n * 16 + (l & 15);
    int k0 = s * 32 + (l >> 4) * 8;
    const float* p = W + o * FAN + k0;
    float v[8];
#pragma unroll
    for (int e = 0; e < 8; e++) v[e] = p[e];
    unsigned hi[4];
    pack8(v, hi);
#pragma unroll
    for (int i = 0; i < 4; i++) wfrag[slot * 4 + i] = hi[i];
  }
}

// ---------- Main: gather + split-A bf16 MFMA GEMM, XCD-batch-coherent ----------
// out ~= (Ah + Al) * Bh : A split to ~17 mantissa bits, W bf16-rounded.
__global__ __launch_bounds__(256, 8) void kmfma(const float* __restrict__ x,
                                                const int* __restrict__ idx,
                                                const float* __restrict__ gcontrib,
                                                const unsigned* __restrict__ wfrag,
                                                float* __restrict__ out) {
  __shared__ __align__(16) unsigned wl[WLN]; // 18432 B -> 8 blocks/CU
  int t = threadIdx.x;
  for (int i = t; i < WLN; i += 256) wl[i] = wfrag[i];
  __syncthreads();

  int bid = blockIdx.x;
  int xcd = bid & 7, slot = bid >> 3;         // bid%8 -> XCD (round-robin dispatch)
  int wid = t >> 6, l = t & 63;
  int ws = slot * 4 + wid;                    // wave slot within XCD, 0..WPX-1
  int lane_lo = l & 15, kg = l >> 4;

  for (int tt = ws; tt < TPX; tt += WPX) {
    int loc = tt, bloc = 0;
    if (loc >= MTILES_PER_B) { loc -= MTILES_PER_B; bloc = 1; }
    int b = 2 * xcd + bloc;
    int nb = loc * 16;
    const float* xb = x + (size_t)b * NN * IC;

    int j[SEQ];
    const int* ip = idx + (nb + lane_lo) * SEQ;
#pragma unroll
    for (int s = 0; s < SEQ; s++) j[s] = ip[s];

    float4 r0[SEQ], r1[SEQ];
#pragma unroll
    for (int s = 0; s < SEQ; s++) {
      const float4* row = (const float4*)(xb + (size_t)j[s] * IC + kg * 8);
      r0[s] = row[0];
      r1[s] = row[1];
    }

    f32x4 acc0 = {0.f, 0.f, 0.f, 0.f};
    f32x4 acc1 = {0.f, 0.f, 0.f, 0.f};

#pragma unroll
    for (int s = 0; s < SEQ; s++) {
      float v[8] = {r0[s].x, r0[s].y, r0[s].z, r0[s].w,
                    r1[s].x, r1[s].y, r1[s].z, r1[s].w};
      FragU ah, al;
      split8(v, ah.u, al.u);

      short8 bh0 = *(const short8*)&wl[(s * 2 + 0) * 256 + (l << 2)];
      short8 bh1 = *(const short8*)&wl[(s * 2 + 1) * 256 + (l << 2)];

      acc0 = __builtin_amdgcn_mfma_f32_16x16x32_bf16(ah.v, bh0, acc0, 0, 0, 0);
      acc0 = __builtin_amdgcn_mfma_f32_16x16x32_bf16(al.v, bh0, acc0, 0, 0, 0);
      acc1 = __builtin_amdgcn_mfma_f32_16x16x32_bf16(ah.v, bh1, acc1, 0, 0, 0);
      acc1 = __builtin_amdgcn_mfma_f32_16x16x32_bf16(al.v, bh1, acc1, 0, 0, 0);
    }

    // D layout: col = lane&15, row = (lane>>4)*4 + reg  [m89-verified]
    float g0 = gcontrib[b * OC + lane_lo];
    float g1 = gcontrib[b * OC + 16 + lane_lo];
#pragma unroll
    for (int jj = 0; jj < 4; jj++) {
      size_t o = ((size_t)b * NN + nb + kg * 4 + jj) * OC;
      __builtin_nontemporal_store(acc0[jj] + g0, &out[o + lane_lo]);
      __builtin_nontemporal_store(acc1[jj] + g1, &out[o + 16 + lane_lo]);
    }
  }
}

extern "C" void kernel_launch(void* const* d_in, const int* in_sizes, int n_in,
                              void* d_out, int out_size, void* d_ws, size_t ws_size,
                              hipStream_t stream) {
  const float* x = (const float*)d_in[0];
  const int* idx = (const int*)d_in[1];
  const float* W = (const float*)d_in[2];
  const float* bias = (const float*)d_in[3];
  float* out = (float*)d_out;

  float* partial = (float*)d_ws;                     // 32768 floats
  float* gcontrib = partial + BS * GROUPS * IC;      // 512 floats
  unsigned* wfrag = (unsigned*)(gcontrib + BS * OC); // 4608 uints (18432 B)

  kmax_partial<<<BS * GROUPS, 256, 0, stream>>>(x, partial);
  kmax_final<<<BS, 64, 0, stream>>>(partial, W, bias, gcontrib);
  kconvW<<<1, 256, 0, stream>>>(W, wfrag);
  kmfma<<<KBLK, 256, 0, stream>>>(x, idx, gcontrib, wfrag, out);
}